// Round 1
// 161.686 us; speedup vs baseline: 1.0094x; 1.0094x over previous
//
#include <hip/hip_runtime.h>
#include <hip/hip_bf16.h>

#define VOCAB 50257
#define EMBED 128
#define NSENT 50
#define TC 20
#define TQ 20
#define BATCH 64
#define NHOPS 3

typedef __bf16 bf16x8 __attribute__((ext_vector_type(8)));
typedef float  f32x4v __attribute__((ext_vector_type(4)));

// ---------------------------------------------------------------------------
// K1: embedding sums. One block per (batch, sentence) for m/c, plus 64 blocks
// for the question embedding u.
// v2: float4-per-lane row gathers -> one 512B transaction per embedding row
// (was 2x 256B from separate waves), 4x fewer VMEM instructions and address
// chains. 8 gather groups of 32 lanes; cross-group reduce through 4KB LDS.
// ---------------------------------------------------------------------------
__global__ void __launch_bounds__(256) k_embed(
    const int* __restrict__ stories, const int* __restrict__ masks,
    const int* __restrict__ questions,
    const float* __restrict__ W_A, const float* __restrict__ W_B,
    const float* __restrict__ W_C,
    const float* __restrict__ W_AT, const float* __restrict__ W_CT,
    float* __restrict__ ws_m, float* __restrict__ ws_c, float* __restrict__ ws_u)
{
    __shared__ float sred[8][128];
    const int blk = blockIdx.x;
    const int tid = threadIdx.x;
    const int grp = tid >> 5;          // 0..7 gather groups (32 lanes each)
    const int gl  = tid & 31;          // lane in group: covers d = gl*4 .. gl*4+3

    if (blk < BATCH * NSENT) {
        const int b = blk / NSENT;
        const int i = blk % NSENT;
        // temporal index: i+1 if any token has mask==0, else 0 (wave-uniform -> s_loads)
        const int* mrow = masks + (b * NSENT + i) * TC;
        int cnt = 0;
        #pragma unroll
        for (int t = 0; t < TC; t++) cnt += (mrow[t] == 0);
        const int te = (cnt >= 1) ? (i + 1) : 0;

        const int* srow = stories + (b * NSENT + i) * TC;
        const int table = grp >> 2;    // groups 0-3 -> A/m, 4-7 -> C/c
        const int sub   = grp & 3;     // token phase within table
        const float* T = table ? W_C : W_A;

        f32x4v acc = {0.f, 0.f, 0.f, 0.f};
        #pragma unroll
        for (int t = 0; t < 5; t++) {
            const int tok = srow[sub + t * 4];
            acc += *(const f32x4v*)(T + (long)tok * EMBED + gl * 4);
        }
        *(f32x4v*)&sred[grp][gl * 4] = acc;
        __syncthreads();

        const int tb = tid >> 7, d = tid & 127;
        const float* TT = tb ? W_CT : W_AT;
        float v = sred[tb * 4 + 0][d] + sred[tb * 4 + 1][d]
                + sred[tb * 4 + 2][d] + sred[tb * 4 + 3][d]
                + TT[te * EMBED + d];
        float* dst = tb ? ws_c : ws_m;
        dst[(b * NSENT + i) * EMBED + d] = v;
    } else {
        const int b = blk - BATCH * NSENT;
        f32x4v acc = {0.f, 0.f, 0.f, 0.f};
        for (int t = grp; t < TQ; t += 8) {          // grp<4: 3 iters, grp>=4: 2 iters
            const int tok = questions[b * TQ + t];
            acc += *(const f32x4v*)(W_B + (long)tok * EMBED + gl * 4);
        }
        *(f32x4v*)&sred[grp][gl * 4] = acc;
        __syncthreads();
        if (tid < EMBED) {
            float v = 0.f;
            #pragma unroll
            for (int g = 0; g < 8; g++) v += sred[g][tid];
            ws_u[b * EMBED + tid] = v;
        }
    }
}

// ---------------------------------------------------------------------------
// K2: 3 hops, one block per batch element, m/c staged in LDS.
// v2: the o = c^T p pass now uses all 256 threads (split the 50-sentence sum
// across two halves, LDS-reduce) instead of 128 threads x 50 serial iters.
// ---------------------------------------------------------------------------
__global__ void __launch_bounds__(256) k_hops(
    const float* __restrict__ ws_m, const float* __restrict__ ws_c,
    const float* __restrict__ ws_u, __bf16* __restrict__ ws_ubf)
{
    __shared__ float smc[2 * NSENT * EMBED];   // [0..6399]=m, [6400..12799]=c
    __shared__ float su[EMBED];
    __shared__ float sp[64];
    __shared__ float ssc[64];
    __shared__ float spo[2][EMBED];

    const int b = blockIdx.x;
    const int tid = threadIdx.x;

    const f32x4v* gm = (const f32x4v*)(ws_m + b * NSENT * EMBED);
    const f32x4v* gc = (const f32x4v*)(ws_c + b * NSENT * EMBED);
    f32x4v* s4 = (f32x4v*)smc;
    for (int idx = tid; idx < NSENT * EMBED / 4; idx += 256) {
        s4[idx] = gm[idx];
        s4[NSENT * EMBED / 4 + idx] = gc[idx];
    }
    if (tid < EMBED) su[tid] = ws_u[b * EMBED + tid];
    __syncthreads();

    const int wave = tid >> 6, lane = tid & 63;
    const int d128 = tid & 127, hf = tid >> 7;
    for (int hop = 0; hop < NHOPS; hop++) {
        // scores: one wave per sentence, shuffle reduce over 64 lanes
        for (int i = wave; i < NSENT; i += 4) {
            float s = smc[i * EMBED + lane] * su[lane]
                    + smc[i * EMBED + 64 + lane] * su[64 + lane];
            #pragma unroll
            for (int off = 32; off >= 1; off >>= 1) s += __shfl_xor(s, off);
            if (lane == 0) ssc[i] = s;
        }
        __syncthreads();
        // softmax over 50 sentences on wave 0
        if (tid < 64) {
            float v = (tid < NSENT) ? ssc[tid] : -1e30f;
            float mx = v;
            #pragma unroll
            for (int off = 32; off >= 1; off >>= 1) mx = fmaxf(mx, __shfl_xor(mx, off));
            float e = (tid < NSENT) ? expf(v - mx) : 0.f;
            float sum = e;
            #pragma unroll
            for (int off = 32; off >= 1; off >>= 1) sum += __shfl_xor(sum, off);
            sp[tid] = e / sum;
        }
        __syncthreads();
        // o = c^T probs, all 256 threads (two 25-sentence half-sums)
        {
            float o = 0.f;
            #pragma unroll
            for (int k = 0; k < 25; k++) {
                const int i = hf * 25 + k;
                o += smc[NSENT * EMBED + i * EMBED + d128] * sp[i];
            }
            spo[hf][d128] = o;
        }
        __syncthreads();
        if (tid < EMBED) su[tid] += spo[0][tid] + spo[1][tid];
        __syncthreads();
    }
    if (tid < EMBED) ws_ubf[b * EMBED + tid] = (__bf16)su[tid];
}

// ---------------------------------------------------------------------------
// K3: out[b][v] = u[b] . W_lin[v] + b_lin[v] via bf16 MFMA 16x16x32.
// v2: 128-v tile per block (wave covers 2 adjacent 16x16 v-subtiles x 64 b);
// accumulators staged through a padded LDS tile so the global stores become
// 256B-contiguous nontemporal bursts per instruction (512B per batch row)
// instead of 64B fragments at 201KB stride.
// ---------------------------------------------------------------------------
#define VT 128
__global__ void __launch_bounds__(256) k_out(
    const __bf16* __restrict__ u_bf, const float* __restrict__ W_lin,
    const float* __restrict__ b_lin, float* __restrict__ out)
{
    __shared__ float sT[64][VT + 1];   // [b][v_local], +1 pad kills quad-row conflicts

    const int tid  = threadIdx.x;
    const int wave = tid >> 6, lane = tid & 63;
    const int m    = lane & 15;
    const int quad = lane >> 4;
    const int vbase = blockIdx.x * VT + wave * 32;

    f32x4v acc[2][4] = {};

    #pragma unroll
    for (int kc = 0; kc < 4; kc++) {
        const int k0 = kc * 32 + quad * 8;
        bf16x8 wb[2];
        #pragma unroll
        for (int s = 0; s < 2; s++) {
            int v = vbase + s * 16 + m;
            int vc = (v < VOCAB) ? v : (VOCAB - 1);
            const float* wrow = W_lin + (long)vc * EMBED;
            f32x4v w0 = *(const f32x4v*)(wrow + k0);
            f32x4v w1 = *(const f32x4v*)(wrow + k0 + 4);
            wb[s][0] = (__bf16)w0[0]; wb[s][1] = (__bf16)w0[1];
            wb[s][2] = (__bf16)w0[2]; wb[s][3] = (__bf16)w0[3];
            wb[s][4] = (__bf16)w1[0]; wb[s][5] = (__bf16)w1[1];
            wb[s][6] = (__bf16)w1[2]; wb[s][7] = (__bf16)w1[3];
        }
        #pragma unroll
        for (int bt = 0; bt < 4; bt++) {
            bf16x8 ab = *(const bf16x8*)(u_bf + (bt * 16 + m) * EMBED + k0);
            acc[0][bt] = __builtin_amdgcn_mfma_f32_16x16x32_bf16(ab, wb[0], acc[0][bt], 0, 0, 0);
            acc[1][bt] = __builtin_amdgcn_mfma_f32_16x16x32_bf16(ab, wb[1], acc[1][bt], 0, 0, 0);
        }
    }

    // C/D layout: row(b) = quad*4 + r, col(v) = m  -> scatter into LDS tile
    #pragma unroll
    for (int s = 0; s < 2; s++)
        #pragma unroll
        for (int bt = 0; bt < 4; bt++)
            #pragma unroll
            for (int r = 0; r < 4; r++)
                sT[bt * 16 + quad * 4 + r][wave * 32 + s * 16 + m] = acc[s][bt][r];
    __syncthreads();

    // coalesced nontemporal stores: 64 lanes x 4B contiguous per instruction
    const int col = tid & 127;
    const int bh  = tid >> 7;
    const int v   = blockIdx.x * VT + col;
    if (v < VOCAB) {
        const float bl = b_lin[v];
        #pragma unroll
        for (int it = 0; it < 32; it++) {
            const int bb = bh * 32 + it;
            __builtin_nontemporal_store(sT[bb][col] + bl, &out[(long)bb * VOCAB + v]);
        }
    }
}

extern "C" void kernel_launch(void* const* d_in, const int* in_sizes, int n_in,
                              void* d_out, int out_size, void* d_ws, size_t ws_size,
                              hipStream_t stream) {
    const int*   stories   = (const int*)d_in[0];
    const int*   questions = (const int*)d_in[1];
    const int*   masks     = (const int*)d_in[2];
    const float* W_A       = (const float*)d_in[3];
    const float* W_B       = (const float*)d_in[4];
    const float* W_C       = (const float*)d_in[5];
    const float* W_AT      = (const float*)d_in[6];
    const float* W_CT      = (const float*)d_in[7];
    const float* W_lin     = (const float*)d_in[8];
    const float* b_lin     = (const float*)d_in[9];
    float* out = (float*)d_out;

    float* ws    = (float*)d_ws;
    float* ws_m  = ws;                                   // 64*50*128 f32
    float* ws_c  = ws + BATCH * NSENT * EMBED;           // 64*50*128 f32
    float* ws_u  = ws + 2 * BATCH * NSENT * EMBED;       // 64*128 f32
    __bf16* ws_ubf = (__bf16*)(ws + 2 * BATCH * NSENT * EMBED + BATCH * EMBED);

    k_embed<<<dim3(BATCH * NSENT + BATCH), dim3(256), 0, stream>>>(
        stories, masks, questions, W_A, W_B, W_C, W_AT, W_CT, ws_m, ws_c, ws_u);
    k_hops<<<dim3(BATCH), dim3(256), 0, stream>>>(ws_m, ws_c, ws_u, ws_ubf);
    k_out<<<dim3((VOCAB + VT - 1) / VT), dim3(256), 0, stream>>>(ws_ubf, W_lin, b_lin, out);
}